// Round 1
// 36404.199 us; speedup vs baseline: 1.1035x; 1.1035x over previous
//
#include <hip/hip_runtime.h>
#include <hip/hip_bf16.h>

// ICE-NODE-like recurrent ODE model on MI355X.
// R2 post-mortem: absmax 22.66 = bf16 drift amplified through 184 chaotic RK4
// substeps. R3: chain + GRU use split-bf16 (hi+lo, 3 MFMAs per product, ~16-bit
// mantissa); fp32 state in LDS. Decoder/embedding are one-shot -> plain bf16 OK.
// R4: chain_k is latency-bound (MfmaUtil 0.87%, 2 waves/SIMD, 16.6us/layer vs
// ~3us weight-delivery floor). Go to 16 waves/WG (1024 thr, 4 waves/SIMD,
// max 2 n-tiles/wave instead of 3) and move the RK ksum accumulator from LDS
// into lane-private registers (ownership is static per lane).

#define B_ 512
#define T_ 24
#define V_ 8000
#define E_ 300
#define M_ 30
#define H_ 330
#define DT_ 0.875f

typedef __bf16 bf16x8 __attribute__((ext_vector_type(8)));
typedef float  f32x4  __attribute__((ext_vector_type(4)));

__device__ __forceinline__ f32x4 MF(bf16x8 a, bf16x8 b, f32x4 c) {
    return __builtin_amdgcn_mfma_f32_16x16x32_bf16(a, b, c, 0, 0, 0);
}
__device__ __forceinline__ float tanhf_(float x) {
    float e = __expf(2.f * x);
    return 1.f - 2.f * __builtin_amdgcn_rcpf(e + 1.f);
}
__device__ __forceinline__ float sigm_(float x) {
    return __builtin_amdgcn_rcpf(1.f + __expf(-x));
}

// ---------------- weight pack: W[n][k] -> MFMA B fragments (hi only) --------
// frag index = (nt*KT + kt)*64 + lane ; element j: B[k=kt*32+quad*8+j][n=nt*16+(lane&15)]
__global__ void pack_b(const float* __restrict__ src, __bf16* __restrict__ dst,
                       int NT, int KT, int Nr, int Kr, int ld) {
    int tid = blockIdx.x * 256 + threadIdx.x;
    int total = NT * KT * 64;
    if (tid >= total) return;
    int L  = tid & 63;
    int kt = (tid >> 6) % KT;
    int nt = tid / (KT * 64);
    int n  = nt * 16 + (L & 15);
    int kb = kt * 32 + ((L >> 4) * 8);
    __bf16* o = dst + (size_t)tid * 8;
#pragma unroll
    for (int j = 0; j < 8; ++j) {
        int k = kb + j;
        float v = (n < Nr && k < Kr) ? src[(size_t)n * ld + k] : 0.f;
        o[j] = (__bf16)v;
    }
}

// ---------------- weight pack: hi + lo (split-bf16) -------------------------
__global__ void pack_hl(const float* __restrict__ src, __bf16* __restrict__ dhi,
                        __bf16* __restrict__ dlo, int NT, int KT, int Nr, int Kr, int ld) {
    int tid = blockIdx.x * 256 + threadIdx.x;
    int total = NT * KT * 64;
    if (tid >= total) return;
    int L  = tid & 63;
    int kt = (tid >> 6) % KT;
    int nt = tid / (KT * 64);
    int n  = nt * 16 + (L & 15);
    int kb = kt * 32 + ((L >> 4) * 8);
    __bf16* oh = dhi + (size_t)tid * 8;
    __bf16* ol = dlo + (size_t)tid * 8;
#pragma unroll
    for (int j = 0; j < 8; ++j) {
        int k = kb + j;
        float v = (n < Nr && k < Kr) ? src[(size_t)n * ld + k] : 0.f;
        __bf16 h = (__bf16)v;
        oh[j] = h;
        ol[j] = (__bf16)(v - (float)h);
    }
}

// ---------------- W_embT[v][e] = W_emb[e][v]  (fp32) ------------------------
__global__ void embt_k(const float* __restrict__ W_emb, float* __restrict__ embT) {
    int tid = blockIdx.x * 256 + threadIdx.x;
    if (tid < V_ * E_) {
        int v = tid / E_, e = tid % E_;
        embT[tid] = W_emb[(size_t)e * V_ + v];
    }
}

// ---------------- W_fused = W_ih @ W_u (90x330), b_fused = W_ih@b_u + b_ih --
__global__ void wfused_k(const float* __restrict__ W_ih, const float* __restrict__ W_u,
                         const float* __restrict__ b_ih, const float* __restrict__ b_u,
                         float* __restrict__ Wf, float* __restrict__ bf_) {
    int tid = blockIdx.x * 256 + threadIdx.x;
    if (tid < 90 * 330) {
        int i = tid / 330, k = tid % 330;
        float acc = 0.f;
        for (int e = 0; e < 300; ++e) acc += W_ih[i * 300 + e] * W_u[e * 330 + k];
        Wf[i * 330 + k] = acc;
    } else if (tid < 90 * 330 + 90) {
        int i = tid - 90 * 330;
        float acc = b_ih[i];
        for (int e = 0; e < 300; ++e) acc += W_ih[i * 300 + e] * b_u[e];
        bf_[i] = acc;
    }
}

// ---------------- sparse embedding: g = codes @ W_emb.T + b_emb -------------
__global__ __launch_bounds__(256) void embed_k(const float* __restrict__ codes,
                                               const float* __restrict__ embT,
                                               const float* __restrict__ b_emb,
                                               float* __restrict__ g) {
    int w = blockIdx.x * 4 + (threadIdx.x >> 6);
    int lane = threadIdx.x & 63;
    float acc[5];
#pragma unroll
    for (int i = 0; i < 5; ++i) {
        int e = lane + 64 * i;
        acc[i] = (e < E_) ? b_emb[e] : 0.f;
    }
    const float4* row = (const float4*)(codes + (size_t)w * V_);
    for (int c = 0; c < 32; ++c) {
        int vi = c * 64 + lane;
        float4 x = make_float4(0.f, 0.f, 0.f, 0.f);
        if (vi < V_ / 4) x = row[vi];
#pragma unroll
        for (int q = 0; q < 4; ++q) {
            float xv = (q == 0) ? x.x : (q == 1) ? x.y : (q == 2) ? x.z : x.w;
            unsigned long long mq = __ballot(xv > 0.5f);
            while (mq) {
                int bit = __ffsll(mq) - 1;
                mq &= mq - 1;
                int j = (c * 64 + bit) * 4 + q;
                const float* er = embT + (size_t)j * E_;
#pragma unroll
                for (int i = 0; i < 5; ++i) {
                    int e = lane + 64 * i;
                    if (e < E_) acc[i] += er[e];
                }
            }
        }
    }
#pragma unroll
    for (int i = 0; i < 5; ++i) {
        int e = lane + 64 * i;
        if (e < E_) g[(size_t)w * E_ + e] = acc[i];
    }
}

// ---------------- chain kernel: persistent recurrence, 16 samples/WG --------
// 16 waves (1024 threads): wave wid owns n-tile wid, plus tile 16+wid if wid<5.
// Split-bf16: every matmul computes ahi*bhi + alo*bhi + ahi*blo (fp32 acc).
// MODE 0: out = tanh(C)                          (ode layers 1,2)
// MODE 1: kreg (=|+=) kw*t ; out = h32 + cdt*t   (k1..k3 final layer)
// MODE 2: h32 += DT/6*(kreg + t); out = h32      (k4 final layer)
// kreg is lane-private (ownership of (m,n) cells is static across layers).
template <int MODE, bool FIRST>
__device__ __forceinline__ void ode_layer(const __bf16* __restrict__ Bh,
                                          const __bf16* __restrict__ Bl,
                                          const __bf16* __restrict__ Ahin,
                                          const __bf16* __restrict__ Alin,
                                          __bf16* __restrict__ Ahout,
                                          __bf16* __restrict__ Alout,
                                          float* __restrict__ h32,
                                          float* __restrict__ kreg,
                                          float kw, float cdt, int wid, int lane) {
    const int quad = lane >> 4, l15 = lane & 15;
    f32x4 z = {0.f, 0.f, 0.f, 0.f};
    f32x4 acc0 = z, acc1 = z;
    const bool has1 = (wid < 5);
#pragma unroll
    for (int kt = 0; kt < 11; ++kt) {
        bf16x8 ah = *(const bf16x8*)(Ahin + l15 * 360 + quad * 8 + kt * 32);
        bf16x8 al = *(const bf16x8*)(Alin + l15 * 360 + quad * 8 + kt * 32);
        size_t f0 = ((size_t)(wid * 11 + kt) * 64 + lane) * 8;
        bf16x8 b0h = *(const bf16x8*)(Bh + f0);
        bf16x8 b0l = *(const bf16x8*)(Bl + f0);
        acc0 = MF(ah, b0h, acc0);
        acc0 = MF(al, b0h, acc0);
        acc0 = MF(ah, b0l, acc0);
        if (has1) {
            size_t f1 = ((size_t)((wid + 16) * 11 + kt) * 64 + lane) * 8;
            bf16x8 b1h = *(const bf16x8*)(Bh + f1);
            bf16x8 b1l = *(const bf16x8*)(Bl + f1);
            acc1 = MF(ah, b1h, acc1);
            acc1 = MF(al, b1h, acc1);
            acc1 = MF(ah, b1l, acc1);
        }
    }
#pragma unroll
    for (int i = 0; i < 2; ++i) {
        if (i == 1 && !has1) break;
        f32x4 acc = (i == 0) ? acc0 : acc1;
        int nt = wid + i * 16;
        int n = nt * 16 + l15;
#pragma unroll
        for (int r = 0; r < 4; ++r) {
            int m = quad * 4 + r;
            float tv = tanhf_(acc[r]);
            float ov;
            if (MODE == 0) {
                ov = tv;
            } else if (MODE == 1) {
                int ix = m * 338 + n;
                float ks = FIRST ? (kw * tv) : (kreg[i * 4 + r] + kw * tv);
                kreg[i * 4 + r] = ks;
                ov = h32[ix] + cdt * tv;
            } else {
                int ix = m * 338 + n;
                float hn = h32[ix] + (DT_ / 6.f) * (kreg[i * 4 + r] + tv);
                h32[ix] = hn;
                ov = hn;
            }
            __bf16 hi = (__bf16)ov;
            Ahout[m * 360 + n] = hi;
            Alout[m * 360 + n] = (__bf16)(ov - (float)hi);
        }
    }
    __syncthreads();
}

__global__ __launch_bounds__(1024, 4) void chain_k(const float* __restrict__ g,
                                                   const __bf16* __restrict__ BpOh,
                                                   const __bf16* __restrict__ BpOl,
                                                   const __bf16* __restrict__ BpFh,
                                                   const __bf16* __restrict__ BpFl,
                                                   const __bf16* __restrict__ BpHh,
                                                   const __bf16* __restrict__ BpHl,
                                                   const float* __restrict__ bfused,
                                                   const float* __restrict__ b_hh,
                                                   __bf16* __restrict__ Hs) {
    __shared__ __align__(16) __bf16 hAh[2 * 5760];  // 16*360
    __shared__ __align__(16) __bf16 hAl[2 * 5760];
    __shared__ __align__(16) __bf16 hGh[5760];
    __shared__ __align__(16) __bf16 hGl[5760];
    __shared__ float h32[16 * 338];
    __shared__ float gxL[16 * 96];
    __shared__ float ghL[16 * 96];

    const int t = threadIdx.x;
    const int lane = t & 63;
    const int wid = t >> 6;
    const int b0 = blockIdx.x * 16;

    float kreg[8];  // lane-private RK ksum: 2 tiles x 4 rows

    __bf16 *Ah0 = hAh, *Ah1 = hAh + 5760;
    __bf16 *Al0 = hAl, *Al1 = hAl + 5760;
    const __bf16* B1h = BpOh;
    const __bf16* B2h = BpOh + 118272;
    const __bf16* B3h = BpOh + 236544;
    const __bf16* B1l = BpOl;
    const __bf16* B2l = BpOl + 118272;
    const __bf16* B3l = BpOl + 236544;

    for (int i = t; i < 2 * 5760; i += 1024) { hAh[i] = (__bf16)0.f; hAl[i] = (__bf16)0.f; }
    for (int i = t; i < 16 * 338; i += 1024) h32[i] = 0.f;
    __syncthreads();
    for (int i = t; i < 16 * 300; i += 1024) {
        int m = i / 300, e = i % 300;
        h32[m * 338 + 30 + e] = g[((size_t)(b0 + m) * T_) * E_ + e];
    }
    __syncthreads();
    for (int i = t; i < 16 * 336; i += 1024) {
        int m = i / 336, c = i % 336;
        float v = h32[m * 338 + c];
        __bf16 hi = (__bf16)v;
        Ah0[m * 360 + c] = hi;
        Al0[m * 360 + c] = (__bf16)(v - (float)hi);
    }
    __syncthreads();

    for (int k = 1; k < T_; ++k) {
        for (int s = 0; s < 8; ++s) {
            ode_layer<0, false>(B1h, B1l, Ah0, Al0, Ah1, Al1, h32, kreg, 0.f, 0.f, wid, lane);
            ode_layer<0, false>(B2h, B2l, Ah1, Al1, Ah0, Al0, h32, kreg, 0.f, 0.f, wid, lane);
            ode_layer<1, true >(B3h, B3l, Ah0, Al0, Ah1, Al1, h32, kreg, 1.f, 0.4375f, wid, lane);
            ode_layer<0, false>(B1h, B1l, Ah1, Al1, Ah0, Al0, h32, kreg, 0.f, 0.f, wid, lane);
            ode_layer<0, false>(B2h, B2l, Ah0, Al0, Ah1, Al1, h32, kreg, 0.f, 0.f, wid, lane);
            ode_layer<1, false>(B3h, B3l, Ah1, Al1, Ah0, Al0, h32, kreg, 2.f, 0.4375f, wid, lane);
            ode_layer<0, false>(B1h, B1l, Ah0, Al0, Ah1, Al1, h32, kreg, 0.f, 0.f, wid, lane);
            ode_layer<0, false>(B2h, B2l, Ah1, Al1, Ah0, Al0, h32, kreg, 0.f, 0.f, wid, lane);
            ode_layer<1, false>(B3h, B3l, Ah0, Al0, Ah1, Al1, h32, kreg, 2.f, 0.875f, wid, lane);
            ode_layer<0, false>(B1h, B1l, Ah1, Al1, Ah0, Al0, h32, kreg, 0.f, 0.f, wid, lane);
            ode_layer<0, false>(B2h, B2l, Ah0, Al0, Ah1, Al1, h32, kreg, 0.f, 0.f, wid, lane);
            ode_layer<2, false>(B3h, B3l, Ah1, Al1, Ah0, Al0, h32, kreg, 0.f, 0.f, wid, lane);
        }
        // stash h_emb (bf16 ok: one-shot path) + build GRU A operand hi/lo
        for (int i = t; i < 16 * 352; i += 1024) {
            int m = i / 352, c = i % 352;
            float v;
            if (c < 30) v = h32[m * 338 + c];
            else if (c < 330) v = g[((size_t)(b0 + m) * T_ + k) * E_ + (c - 30)];
            else v = 0.f;
            __bf16 hi = (__bf16)v;
            hGh[m * 360 + c] = hi;
            hGl[m * 360 + c] = (__bf16)(v - (float)hi);
        }
        for (int i = t; i < 16 * 320; i += 1024) {
            int m = i / 320, c = i % 320;
            Hs[((size_t)(k - 1) * B_ + b0 + m) * 320 + c] =
                (c < 300) ? (__bf16)h32[m * 338 + 30 + c] : (__bf16)0.f;
        }
        __syncthreads();
        // gx = cat(h_mem,g_k) @ W_fused^T + b_fused ; gh = h_mem @ W_hh^T + b_hh
        if (wid < 6) {
            const int quad = lane >> 4, l15 = lane & 15;
            f32x4 z = {0.f, 0.f, 0.f, 0.f};
            f32x4 ax = z, ah = z;
#pragma unroll
            for (int kt = 0; kt < 11; ++kt) {
                bf16x8 xh = *(const bf16x8*)(hGh + l15 * 360 + quad * 8 + kt * 32);
                bf16x8 xl = *(const bf16x8*)(hGl + l15 * 360 + quad * 8 + kt * 32);
                size_t f = ((size_t)(wid * 11 + kt) * 64 + lane) * 8;
                bf16x8 bh = *(const bf16x8*)(BpFh + f);
                bf16x8 bl = *(const bf16x8*)(BpFl + f);
                ax = MF(xh, bh, ax);
                ax = MF(xl, bh, ax);
                ax = MF(xh, bl, ax);
            }
            {
                bf16x8 xh = *(const bf16x8*)(hGh + l15 * 360 + quad * 8);
                bf16x8 xl = *(const bf16x8*)(hGl + l15 * 360 + quad * 8);
                size_t f = (size_t)(wid * 64 + lane) * 8;
                bf16x8 bh = *(const bf16x8*)(BpHh + f);
                bf16x8 bl = *(const bf16x8*)(BpHl + f);
                ah = MF(xh, bh, ah);   // k=30,31 slots carry g but B rows are zero
                ah = MF(xl, bh, ah);
                ah = MF(xh, bl, ah);
            }
            int n = wid * 16 + l15;
            if (n < 90) {
#pragma unroll
                for (int r = 0; r < 4; ++r) {
                    int m = quad * 4 + r;
                    gxL[m * 96 + n] = ax[r] + bfused[n];
                    ghL[m * 96 + n] = ah[r] + b_hh[n];
                }
            }
        }
        __syncthreads();
        if (t < 480) {
            int m = t / 30, j = t % 30;
            float xr = gxL[m * 96 + j], xz = gxL[m * 96 + 30 + j], xn = gxL[m * 96 + 60 + j];
            float hr = ghL[m * 96 + j], hz = ghL[m * 96 + 30 + j], hn = ghL[m * 96 + 60 + j];
            float rr = sigm_(xr + hr);
            float zz = sigm_(xz + hz);
            float nn = tanhf_(xn + rr * hn);
            float hv = h32[m * 338 + j];
            h32[m * 338 + j] = (1.f - zz) * nn + zz * hv;
        }
        __syncthreads();
        if (t < 512) {
            int m = t >> 5, j = t & 31;
            if (j < 30) {
                float v = h32[m * 338 + j];
                __bf16 hi = (__bf16)v;
                Ah0[m * 360 + j] = hi;
                Al0[m * 360 + j] = (__bf16)(v - (float)hi);
            }
        }
        __syncthreads();
    }
}

// ---------------- decoder stage 1: X1 = lrelu(Hs @ W_d1^T + b_d1) -----------
__global__ __launch_bounds__(256) void dec1_k(const __bf16* __restrict__ Hs,
                                              const __bf16* __restrict__ BpD1,
                                              const float* __restrict__ b_d1,
                                              __bf16* __restrict__ X1) {
    __shared__ __align__(16) __bf16 As[16 * 328];
    int t = threadIdx.x, lane = t & 63, wid = t >> 6;
    int quad = lane >> 4, l15 = lane & 15;
    int m0 = blockIdx.x * 16;
    for (int c8 = t; c8 < 640; c8 += 256) {
        int row = c8 / 40, col8 = c8 % 40;
        *(bf16x8*)(As + row * 328 + col8 * 8) =
            *(const bf16x8*)(Hs + (size_t)(m0 + row) * 320 + col8 * 8);
    }
    __syncthreads();
    f32x4 z = {0.f, 0.f, 0.f, 0.f};
    f32x4 acc[5] = {z, z, z, z, z};
#pragma unroll
    for (int kt = 0; kt < 10; ++kt) {
        bf16x8 a = *(const bf16x8*)(As + l15 * 328 + quad * 8 + kt * 32);
#pragma unroll
        for (int i = 0; i < 5; ++i) {
            int nt = wid + i * 4;
            if (nt < 19) {
                bf16x8 b = *(const bf16x8*)(BpD1 + ((size_t)(nt * 10 + kt) * 64 + lane) * 8);
                acc[i] = MF(a, b, acc[i]);
            }
        }
    }
#pragma unroll
    for (int i = 0; i < 5; ++i) {
        int nt = wid + i * 4;
        if (nt >= 19) break;
        int n = nt * 16 + l15;
#pragma unroll
        for (int r = 0; r < 4; ++r) {
            int m = quad * 4 + r;
            float v = 0.f;
            if (n < 300) {
                v = acc[i][r] + b_d1[n];
                v = (v > 0.f) ? v : 0.01f * v;
            }
            X1[(size_t)(m0 + m) * 320 + n] = (__bf16)v;
        }
    }
    { // zero pad cols 304..319
        int m = t >> 4, c = 304 + (t & 15);
        X1[(size_t)(m0 + m) * 320 + c] = (__bf16)0.f;
    }
}

// ---------------- decoder stage 2: logits = X1 @ W_d2^T + b_d2 (masked) -----
__global__ __launch_bounds__(512) void dec2_k(const __bf16* __restrict__ X1,
                                              const __bf16* __restrict__ BpD2,
                                              const float* __restrict__ b_d2,
                                              const int* __restrict__ lengths,
                                              float* __restrict__ out) {
    __shared__ __align__(16) __bf16 As[64 * 328];
    __shared__ int validL[64];
    __shared__ int obase[64];
    int t = threadIdx.x, lane = t & 63, wid = t >> 6;
    int quad = lane >> 4, l15 = lane & 15;
    int mchunk = blockIdx.x % 184, nchunk = blockIdx.x / 184;
    int m0 = mchunk * 64;
    for (int c8 = t; c8 < 2560; c8 += 512) {
        int row = c8 / 40, col8 = c8 % 40;
        *(bf16x8*)(As + row * 328 + col8 * 8) =
            *(const bf16x8*)(X1 + (size_t)(m0 + row) * 320 + col8 * 8);
    }
    if (t < 64) {
        int row = m0 + t;
        int k = (row >> 9) + 1, b = row & 511;
        // dtype hedge: if lengths is int64, its int32 view has 0 at odd index
        // (values are 2..24, always >=2, so lengths32[1]==0 <=> int64).
        int is64 = (lengths[1] == 0);
        int lb = is64 ? lengths[2 * b] : lengths[b];
        validL[t] = (k < lb);
        obase[t] = b * ((T_ - 1) * V_) + (k - 1) * V_;
    }
    __syncthreads();
    int mt = wid >> 1, nb = (wid & 1) * 8;
    f32x4 z = {0.f, 0.f, 0.f, 0.f};
    f32x4 acc[8] = {z, z, z, z, z, z, z, z};
#pragma unroll
    for (int kt = 0; kt < 10; ++kt) {
        bf16x8 a = *(const bf16x8*)(As + (mt * 16 + l15) * 328 + quad * 8 + kt * 32);
#pragma unroll
        for (int j = 0; j < 8; ++j) {
            int ntg = nchunk * 16 + nb + j;
            if (ntg < 500) {
                bf16x8 b = *(const bf16x8*)(BpD2 + ((size_t)ntg * 10 + kt) * 64 * 8 + lane * 8);
                acc[j] = MF(a, b, acc[j]);
            }
        }
    }
#pragma unroll
    for (int j = 0; j < 8; ++j) {
        int ntg = nchunk * 16 + nb + j;
        if (ntg >= 500) break;
        int n = ntg * 16 + l15;
        float bias = b_d2[n];
#pragma unroll
        for (int r = 0; r < 4; ++r) {
            int m = mt * 16 + quad * 4 + r;
            float v = validL[m] ? (acc[j][r] + bias) : 0.f;
            out[(size_t)obase[m] + n] = v;
        }
    }
}

// ---------------------------------------------------------------------------
extern "C" void kernel_launch(void* const* d_in, const int* in_sizes, int n_in,
                              void* d_out, int out_size, void* d_ws, size_t ws_size,
                              hipStream_t stream) {
    const float* codes = (const float*)d_in[1];
    const int* lengths = (const int*)d_in[2];
    const float* W_emb = (const float*)d_in[3];
    const float* b_emb = (const float*)d_in[4];
    const float* W1 = (const float*)d_in[5];
    const float* W2 = (const float*)d_in[6];
    const float* W3 = (const float*)d_in[7];
    const float* W_u = (const float*)d_in[8];
    const float* b_u = (const float*)d_in[9];
    const float* W_ih = (const float*)d_in[10];
    const float* W_hh = (const float*)d_in[11];
    const float* b_ih = (const float*)d_in[12];
    const float* b_hh = (const float*)d_in[13];
    const float* W_d1 = (const float*)d_in[14];
    const float* b_d1 = (const float*)d_in[15];
    const float* W_d2 = (const float*)d_in[16];
    const float* b_d2 = (const float*)d_in[17];
    float* out = (float*)d_out;

    char* ws = (char*)d_ws;
    size_t off = 0;
    auto alloc = [&](size_t bytes) {
        size_t r = off;
        off += (bytes + 255) & ~(size_t)255;
        return r;
    };
    float*  g    = (float*)(ws + alloc((size_t)B_ * T_ * E_ * 4));
    float*  embT = (float*)(ws + alloc((size_t)V_ * E_ * 4));
    __bf16* BpOh = (__bf16*)(ws + alloc((size_t)3 * 21 * 11 * 64 * 8 * 2));
    __bf16* BpOl = (__bf16*)(ws + alloc((size_t)3 * 21 * 11 * 64 * 8 * 2));
    __bf16* BpFh = (__bf16*)(ws + alloc((size_t)6 * 11 * 64 * 8 * 2));
    __bf16* BpFl = (__bf16*)(ws + alloc((size_t)6 * 11 * 64 * 8 * 2));
    __bf16* BpHh = (__bf16*)(ws + alloc((size_t)6 * 1 * 64 * 8 * 2));
    __bf16* BpHl = (__bf16*)(ws + alloc((size_t)6 * 1 * 64 * 8 * 2));
    float*  Wf   = (float*)(ws + alloc((size_t)90 * 330 * 4));
    float*  bf_  = (float*)(ws + alloc((size_t)90 * 4));
    __bf16* Hs   = (__bf16*)(ws + alloc((size_t)11776 * 320 * 2));
    __bf16* X1   = (__bf16*)(ws + alloc((size_t)11776 * 320 * 2));
    __bf16* BpD1 = (__bf16*)(ws + alloc((size_t)19 * 10 * 64 * 8 * 2));
    __bf16* BpD2 = (__bf16*)(ws + alloc((size_t)500 * 10 * 64 * 8 * 2));

    // weight packing (hi/lo for the recurrent path)
    pack_hl<<<58, 256, 0, stream>>>(W1, BpOh, BpOl, 21, 11, 330, 330, 330);
    pack_hl<<<58, 256, 0, stream>>>(W2, BpOh + 118272, BpOl + 118272, 21, 11, 330, 330, 330);
    pack_hl<<<58, 256, 0, stream>>>(W3, BpOh + 236544, BpOl + 236544, 21, 11, 330, 330, 330);
    pack_hl<<<2, 256, 0, stream>>>(W_hh, BpHh, BpHl, 6, 1, 90, 30, 30);
    pack_b<<<48, 256, 0, stream>>>(W_d1, BpD1, 19, 10, 300, 300, 300);
    pack_b<<<1250, 256, 0, stream>>>(W_d2, BpD2, 500, 10, 8000, 300, 300);
    embt_k<<<9375, 256, 0, stream>>>(W_emb, embT);
    wfused_k<<<117, 256, 0, stream>>>(W_ih, W_u, b_ih, b_u, Wf, bf_);
    pack_hl<<<17, 256, 0, stream>>>(Wf, BpFh, BpFl, 6, 11, 90, 330, 330);

    // embedding
    embed_k<<<3072, 256, 0, stream>>>(codes, embT, b_emb, g);

    // recurrent chain (the critical path)
    chain_k<<<32, 1024, 0, stream>>>(g, BpOh, BpOl, BpFh, BpFl, BpHh, BpHl, bf_, b_hh, Hs);

    // decoder
    dec1_k<<<736, 256, 0, stream>>>(Hs, BpD1, b_d1, X1);
    dec2_k<<<184 * 32, 512, 0, stream>>>(X1, BpD2, b_d2, lengths, out);
}

// Round 2
// 18836.913 us; speedup vs baseline: 2.1327x; 1.9326x over previous
//
#include <hip/hip_runtime.h>
#include <hip/hip_bf16.h>

// ICE-NODE-like recurrent ODE model on MI355X.
// R2 post-mortem: absmax 22.66 = bf16 drift through 184 chaotic RK4 substeps.
// R3: chain + GRU use split-bf16 (hi+lo, 3 MFMAs per product); fp32 state in LDS.
// R4: 16 waves/WG + reg-resident ksum. Occupancy doubled but only -9%: VGPR=64
// left no room for in-flight loads -> 44 serial ~830cy B-load round-trips/layer
// = 15.2us/layer (matches measured exactly).
// R5: explicit depth-8 rolling register buffer for B fragments (software
// pipeline, static indices via full unroll). 22-step interleaved tile0/tile1
// stream; steady-state ~115cy/step instead of ~830. Same MFMA order ->
// bit-identical numerics.

#define B_ 512
#define T_ 24
#define V_ 8000
#define E_ 300
#define M_ 30
#define H_ 330
#define DT_ 0.875f

typedef __bf16 bf16x8 __attribute__((ext_vector_type(8)));
typedef float  f32x4  __attribute__((ext_vector_type(4)));

__device__ __forceinline__ f32x4 MF(bf16x8 a, bf16x8 b, f32x4 c) {
    return __builtin_amdgcn_mfma_f32_16x16x32_bf16(a, b, c, 0, 0, 0);
}
__device__ __forceinline__ float tanhf_(float x) {
    float e = __expf(2.f * x);
    return 1.f - 2.f * __builtin_amdgcn_rcpf(e + 1.f);
}
__device__ __forceinline__ float sigm_(float x) {
    return __builtin_amdgcn_rcpf(1.f + __expf(-x));
}

// ---------------- weight pack: W[n][k] -> MFMA B fragments (hi only) --------
// frag index = (nt*KT + kt)*64 + lane ; element j: B[k=kt*32+quad*8+j][n=nt*16+(lane&15)]
__global__ void pack_b(const float* __restrict__ src, __bf16* __restrict__ dst,
                       int NT, int KT, int Nr, int Kr, int ld) {
    int tid = blockIdx.x * 256 + threadIdx.x;
    int total = NT * KT * 64;
    if (tid >= total) return;
    int L  = tid & 63;
    int kt = (tid >> 6) % KT;
    int nt = tid / (KT * 64);
    int n  = nt * 16 + (L & 15);
    int kb = kt * 32 + ((L >> 4) * 8);
    __bf16* o = dst + (size_t)tid * 8;
#pragma unroll
    for (int j = 0; j < 8; ++j) {
        int k = kb + j;
        float v = (n < Nr && k < Kr) ? src[(size_t)n * ld + k] : 0.f;
        o[j] = (__bf16)v;
    }
}

// ---------------- weight pack: hi + lo (split-bf16) -------------------------
__global__ void pack_hl(const float* __restrict__ src, __bf16* __restrict__ dhi,
                        __bf16* __restrict__ dlo, int NT, int KT, int Nr, int Kr, int ld) {
    int tid = blockIdx.x * 256 + threadIdx.x;
    int total = NT * KT * 64;
    if (tid >= total) return;
    int L  = tid & 63;
    int kt = (tid >> 6) % KT;
    int nt = tid / (KT * 64);
    int n  = nt * 16 + (L & 15);
    int kb = kt * 32 + ((L >> 4) * 8);
    __bf16* oh = dhi + (size_t)tid * 8;
    __bf16* ol = dlo + (size_t)tid * 8;
#pragma unroll
    for (int j = 0; j < 8; ++j) {
        int k = kb + j;
        float v = (n < Nr && k < Kr) ? src[(size_t)n * ld + k] : 0.f;
        __bf16 h = (__bf16)v;
        oh[j] = h;
        ol[j] = (__bf16)(v - (float)h);
    }
}

// ---------------- W_embT[v][e] = W_emb[e][v]  (fp32) ------------------------
__global__ void embt_k(const float* __restrict__ W_emb, float* __restrict__ embT) {
    int tid = blockIdx.x * 256 + threadIdx.x;
    if (tid < V_ * E_) {
        int v = tid / E_, e = tid % E_;
        embT[tid] = W_emb[(size_t)e * V_ + v];
    }
}

// ---------------- W_fused = W_ih @ W_u (90x330), b_fused = W_ih@b_u + b_ih --
__global__ void wfused_k(const float* __restrict__ W_ih, const float* __restrict__ W_u,
                         const float* __restrict__ b_ih, const float* __restrict__ b_u,
                         float* __restrict__ Wf, float* __restrict__ bf_) {
    int tid = blockIdx.x * 256 + threadIdx.x;
    if (tid < 90 * 330) {
        int i = tid / 330, k = tid % 330;
        float acc = 0.f;
        for (int e = 0; e < 300; ++e) acc += W_ih[i * 300 + e] * W_u[e * 330 + k];
        Wf[i * 330 + k] = acc;
    } else if (tid < 90 * 330 + 90) {
        int i = tid - 90 * 330;
        float acc = b_ih[i];
        for (int e = 0; e < 300; ++e) acc += W_ih[i * 300 + e] * b_u[e];
        bf_[i] = acc;
    }
}

// ---------------- sparse embedding: g = codes @ W_emb.T + b_emb -------------
__global__ __launch_bounds__(256) void embed_k(const float* __restrict__ codes,
                                               const float* __restrict__ embT,
                                               const float* __restrict__ b_emb,
                                               float* __restrict__ g) {
    int w = blockIdx.x * 4 + (threadIdx.x >> 6);
    int lane = threadIdx.x & 63;
    float acc[5];
#pragma unroll
    for (int i = 0; i < 5; ++i) {
        int e = lane + 64 * i;
        acc[i] = (e < E_) ? b_emb[e] : 0.f;
    }
    const float4* row = (const float4*)(codes + (size_t)w * V_);
    for (int c = 0; c < 32; ++c) {
        int vi = c * 64 + lane;
        float4 x = make_float4(0.f, 0.f, 0.f, 0.f);
        if (vi < V_ / 4) x = row[vi];
#pragma unroll
        for (int q = 0; q < 4; ++q) {
            float xv = (q == 0) ? x.x : (q == 1) ? x.y : (q == 2) ? x.z : x.w;
            unsigned long long mq = __ballot(xv > 0.5f);
            while (mq) {
                int bit = __ffsll(mq) - 1;
                mq &= mq - 1;
                int j = (c * 64 + bit) * 4 + q;
                const float* er = embT + (size_t)j * E_;
#pragma unroll
                for (int i = 0; i < 5; ++i) {
                    int e = lane + 64 * i;
                    if (e < E_) acc[i] += er[e];
                }
            }
        }
    }
#pragma unroll
    for (int i = 0; i < 5; ++i) {
        int e = lane + 64 * i;
        if (e < E_) g[(size_t)w * E_ + e] = acc[i];
    }
}

// ---------------- software-pipelined split-bf16 matmul core -----------------
// Stream of NS steps (TWO: 22 = 11 kt x 2 tiles interleaved; else 11 = 1 tile).
// Depth-8 rolling register buffer of B fragments; loads issued 8 steps ahead.
// MFMA order per acc chain identical to the unpipelined version (numerics!).
template <bool TWO>
__device__ __forceinline__ void mm_pipe(const __bf16* __restrict__ Bh,
                                        const __bf16* __restrict__ Bl,
                                        const __bf16* __restrict__ Ah,
                                        const __bf16* __restrict__ Al,
                                        int wid, int lane,
                                        f32x4& acc0, f32x4& acc1) {
    const int quad = lane >> 4, l15 = lane & 15;
    constexpr int NS = TWO ? 22 : 11;
    constexpr int D = 8;
    bf16x8 pbh[D], pbl[D];
    const __bf16* b0h = Bh + ((size_t)wid * 11 * 64 + lane) * 8;
    const __bf16* b0l = Bl + ((size_t)wid * 11 * 64 + lane) * 8;
    const __bf16* b1h = Bh + ((size_t)(wid + 16) * 11 * 64 + lane) * 8;
    const __bf16* b1l = Bl + ((size_t)(wid + 16) * 11 * 64 + lane) * 8;
#pragma unroll
    for (int s = 0; s < D; ++s) {
        const int tile = TWO ? (s & 1) : 0;
        const int kt   = TWO ? (s >> 1) : s;
        pbh[s] = *(const bf16x8*)((tile ? b1h : b0h) + kt * 512);
        pbl[s] = *(const bf16x8*)((tile ? b1l : b0l) + kt * 512);
    }
#pragma unroll
    for (int s = 0; s < NS; ++s) {
        const int tile = TWO ? (s & 1) : 0;
        const int kt   = TWO ? (s >> 1) : s;
        bf16x8 a_h = *(const bf16x8*)(Ah + l15 * 360 + quad * 8 + kt * 32);
        bf16x8 a_l = *(const bf16x8*)(Al + l15 * 360 + quad * 8 + kt * 32);
        bf16x8 w_h = pbh[s % D];
        bf16x8 w_l = pbl[s % D];
        if (s + D < NS) {
            const int s2 = s + D;
            const int t2 = TWO ? (s2 & 1) : 0;
            const int k2 = TWO ? (s2 >> 1) : s2;
            pbh[s % D] = *(const bf16x8*)((t2 ? b1h : b0h) + k2 * 512);
            pbl[s % D] = *(const bf16x8*)((t2 ? b1l : b0l) + k2 * 512);
        }
        f32x4& acc = (TWO && tile) ? acc1 : acc0;
        acc = MF(a_h, w_h, acc);
        acc = MF(a_l, w_h, acc);
        acc = MF(a_h, w_l, acc);
    }
}

// ---------------- chain kernel: persistent recurrence, 16 samples/WG --------
// 16 waves (1024 threads): wave wid owns n-tile wid, plus tile 16+wid if wid<5.
// MODE 0: out = tanh(C)                          (ode layers 1,2)
// MODE 1: kreg (=|+=) kw*t ; out = h32 + cdt*t   (k1..k3 final layer)
// MODE 2: h32 += DT/6*(kreg + t); out = h32      (k4 final layer)
template <int MODE, bool FIRST>
__device__ __forceinline__ void ode_layer(const __bf16* __restrict__ Bh,
                                          const __bf16* __restrict__ Bl,
                                          const __bf16* __restrict__ Ahin,
                                          const __bf16* __restrict__ Alin,
                                          __bf16* __restrict__ Ahout,
                                          __bf16* __restrict__ Alout,
                                          float* __restrict__ h32,
                                          float* __restrict__ kreg,
                                          float kw, float cdt, int wid, int lane) {
    const int quad = lane >> 4, l15 = lane & 15;
    f32x4 z = {0.f, 0.f, 0.f, 0.f};
    f32x4 acc0 = z, acc1 = z;
    const bool has1 = (wid < 5);
    if (has1) mm_pipe<true >(Bh, Bl, Ahin, Alin, wid, lane, acc0, acc1);
    else      mm_pipe<false>(Bh, Bl, Ahin, Alin, wid, lane, acc0, acc1);
#pragma unroll
    for (int i = 0; i < 2; ++i) {
        if (i == 1 && !has1) break;
        f32x4 acc = (i == 0) ? acc0 : acc1;
        int nt = wid + i * 16;
        int n = nt * 16 + l15;
#pragma unroll
        for (int r = 0; r < 4; ++r) {
            int m = quad * 4 + r;
            float tv = tanhf_(acc[r]);
            float ov;
            if (MODE == 0) {
                ov = tv;
            } else if (MODE == 1) {
                int ix = m * 338 + n;
                float ks = FIRST ? (kw * tv) : (kreg[i * 4 + r] + kw * tv);
                kreg[i * 4 + r] = ks;
                ov = h32[ix] + cdt * tv;
            } else {
                int ix = m * 338 + n;
                float hn = h32[ix] + (DT_ / 6.f) * (kreg[i * 4 + r] + tv);
                h32[ix] = hn;
                ov = hn;
            }
            __bf16 hi = (__bf16)ov;
            Ahout[m * 360 + n] = hi;
            Alout[m * 360 + n] = (__bf16)(ov - (float)hi);
        }
    }
    __syncthreads();
}

__global__ __launch_bounds__(1024, 4) void chain_k(const float* __restrict__ g,
                                                   const __bf16* __restrict__ BpOh,
                                                   const __bf16* __restrict__ BpOl,
                                                   const __bf16* __restrict__ BpFh,
                                                   const __bf16* __restrict__ BpFl,
                                                   const __bf16* __restrict__ BpHh,
                                                   const __bf16* __restrict__ BpHl,
                                                   const float* __restrict__ bfused,
                                                   const float* __restrict__ b_hh,
                                                   __bf16* __restrict__ Hs) {
    __shared__ __align__(16) __bf16 hAh[2 * 5760];  // 16*360
    __shared__ __align__(16) __bf16 hAl[2 * 5760];
    __shared__ __align__(16) __bf16 hGh[5760];
    __shared__ __align__(16) __bf16 hGl[5760];
    __shared__ float h32[16 * 338];
    __shared__ float gxL[16 * 96];
    __shared__ float ghL[16 * 96];

    const int t = threadIdx.x;
    const int lane = t & 63;
    const int wid = t >> 6;
    const int b0 = blockIdx.x * 16;

    float kreg[8];  // lane-private RK ksum: 2 tiles x 4 rows

    __bf16 *Ah0 = hAh, *Ah1 = hAh + 5760;
    __bf16 *Al0 = hAl, *Al1 = hAl + 5760;
    const __bf16* B1h = BpOh;
    const __bf16* B2h = BpOh + 118272;
    const __bf16* B3h = BpOh + 236544;
    const __bf16* B1l = BpOl;
    const __bf16* B2l = BpOl + 118272;
    const __bf16* B3l = BpOl + 236544;

    for (int i = t; i < 2 * 5760; i += 1024) { hAh[i] = (__bf16)0.f; hAl[i] = (__bf16)0.f; }
    for (int i = t; i < 16 * 338; i += 1024) h32[i] = 0.f;
    __syncthreads();
    for (int i = t; i < 16 * 300; i += 1024) {
        int m = i / 300, e = i % 300;
        h32[m * 338 + 30 + e] = g[((size_t)(b0 + m) * T_) * E_ + e];
    }
    __syncthreads();
    for (int i = t; i < 16 * 336; i += 1024) {
        int m = i / 336, c = i % 336;
        float v = h32[m * 338 + c];
        __bf16 hi = (__bf16)v;
        Ah0[m * 360 + c] = hi;
        Al0[m * 360 + c] = (__bf16)(v - (float)hi);
    }
    __syncthreads();

    for (int k = 1; k < T_; ++k) {
        for (int s = 0; s < 8; ++s) {
            ode_layer<0, false>(B1h, B1l, Ah0, Al0, Ah1, Al1, h32, kreg, 0.f, 0.f, wid, lane);
            ode_layer<0, false>(B2h, B2l, Ah1, Al1, Ah0, Al0, h32, kreg, 0.f, 0.f, wid, lane);
            ode_layer<1, true >(B3h, B3l, Ah0, Al0, Ah1, Al1, h32, kreg, 1.f, 0.4375f, wid, lane);
            ode_layer<0, false>(B1h, B1l, Ah1, Al1, Ah0, Al0, h32, kreg, 0.f, 0.f, wid, lane);
            ode_layer<0, false>(B2h, B2l, Ah0, Al0, Ah1, Al1, h32, kreg, 0.f, 0.f, wid, lane);
            ode_layer<1, false>(B3h, B3l, Ah1, Al1, Ah0, Al0, h32, kreg, 2.f, 0.4375f, wid, lane);
            ode_layer<0, false>(B1h, B1l, Ah0, Al0, Ah1, Al1, h32, kreg, 0.f, 0.f, wid, lane);
            ode_layer<0, false>(B2h, B2l, Ah1, Al1, Ah0, Al0, h32, kreg, 0.f, 0.f, wid, lane);
            ode_layer<1, false>(B3h, B3l, Ah0, Al0, Ah1, Al1, h32, kreg, 2.f, 0.875f, wid, lane);
            ode_layer<0, false>(B1h, B1l, Ah1, Al1, Ah0, Al0, h32, kreg, 0.f, 0.f, wid, lane);
            ode_layer<0, false>(B2h, B2l, Ah0, Al0, Ah1, Al1, h32, kreg, 0.f, 0.f, wid, lane);
            ode_layer<2, false>(B3h, B3l, Ah1, Al1, Ah0, Al0, h32, kreg, 0.f, 0.f, wid, lane);
        }
        // stash h_emb (bf16 ok: one-shot path) + build GRU A operand hi/lo
        for (int i = t; i < 16 * 352; i += 1024) {
            int m = i / 352, c = i % 352;
            float v;
            if (c < 30) v = h32[m * 338 + c];
            else if (c < 330) v = g[((size_t)(b0 + m) * T_ + k) * E_ + (c - 30)];
            else v = 0.f;
            __bf16 hi = (__bf16)v;
            hGh[m * 360 + c] = hi;
            hGl[m * 360 + c] = (__bf16)(v - (float)hi);
        }
        for (int i = t; i < 16 * 320; i += 1024) {
            int m = i / 320, c = i % 320;
            Hs[((size_t)(k - 1) * B_ + b0 + m) * 320 + c] =
                (c < 300) ? (__bf16)h32[m * 338 + 30 + c] : (__bf16)0.f;
        }
        __syncthreads();
        // gx = cat(h_mem,g_k) @ W_fused^T + b_fused ; gh = h_mem @ W_hh^T + b_hh
        if (wid < 6) {
            const int quad = lane >> 4, l15 = lane & 15;
            f32x4 z = {0.f, 0.f, 0.f, 0.f};
            f32x4 ax = z, dum = z, ahh = z;
            // W_hh fragment loads issued up-front; latency hides under mm_pipe
            bf16x8 hbh = *(const bf16x8*)(BpHh + (size_t)(wid * 64 + lane) * 8);
            bf16x8 hbl = *(const bf16x8*)(BpHl + (size_t)(wid * 64 + lane) * 8);
            bf16x8 xh0 = *(const bf16x8*)(hGh + l15 * 360 + quad * 8);
            bf16x8 xl0 = *(const bf16x8*)(hGl + l15 * 360 + quad * 8);
            mm_pipe<false>(BpFh, BpFl, hGh, hGl, wid, lane, ax, dum);
            ahh = MF(xh0, hbh, ahh);   // k=30,31 slots carry g but B rows are zero
            ahh = MF(xl0, hbh, ahh);
            ahh = MF(xh0, hbl, ahh);
            int n = wid * 16 + l15;
            if (n < 90) {
#pragma unroll
                for (int r = 0; r < 4; ++r) {
                    int m = quad * 4 + r;
                    gxL[m * 96 + n] = ax[r] + bfused[n];
                    ghL[m * 96 + n] = ahh[r] + b_hh[n];
                }
            }
        }
        __syncthreads();
        if (t < 480) {
            int m = t / 30, j = t % 30;
            float xr = gxL[m * 96 + j], xz = gxL[m * 96 + 30 + j], xn = gxL[m * 96 + 60 + j];
            float hr = ghL[m * 96 + j], hz = ghL[m * 96 + 30 + j], hn = ghL[m * 96 + 60 + j];
            float rr = sigm_(xr + hr);
            float zz = sigm_(xz + hz);
            float nn = tanhf_(xn + rr * hn);
            float hv = h32[m * 338 + j];
            h32[m * 338 + j] = (1.f - zz) * nn + zz * hv;
        }
        __syncthreads();
        if (t < 512) {
            int m = t >> 5, j = t & 31;
            if (j < 30) {
                float v = h32[m * 338 + j];
                __bf16 hi = (__bf16)v;
                Ah0[m * 360 + j] = hi;
                Al0[m * 360 + j] = (__bf16)(v - (float)hi);
            }
        }
        __syncthreads();
    }
}

// ---------------- decoder stage 1: X1 = lrelu(Hs @ W_d1^T + b_d1) -----------
__global__ __launch_bounds__(256) void dec1_k(const __bf16* __restrict__ Hs,
                                              const __bf16* __restrict__ BpD1,
                                              const float* __restrict__ b_d1,
                                              __bf16* __restrict__ X1) {
    __shared__ __align__(16) __bf16 As[16 * 328];
    int t = threadIdx.x, lane = t & 63, wid = t >> 6;
    int quad = lane >> 4, l15 = lane & 15;
    int m0 = blockIdx.x * 16;
    for (int c8 = t; c8 < 640; c8 += 256) {
        int row = c8 / 40, col8 = c8 % 40;
        *(bf16x8*)(As + row * 328 + col8 * 8) =
            *(const bf16x8*)(Hs + (size_t)(m0 + row) * 320 + col8 * 8);
    }
    __syncthreads();
    f32x4 z = {0.f, 0.f, 0.f, 0.f};
    f32x4 acc[5] = {z, z, z, z, z};
#pragma unroll
    for (int kt = 0; kt < 10; ++kt) {
        bf16x8 a = *(const bf16x8*)(As + l15 * 328 + quad * 8 + kt * 32);
#pragma unroll
        for (int i = 0; i < 5; ++i) {
            int nt = wid + i * 4;
            if (nt < 19) {
                bf16x8 b = *(const bf16x8*)(BpD1 + ((size_t)(nt * 10 + kt) * 64 + lane) * 8);
                acc[i] = MF(a, b, acc[i]);
            }
        }
    }
#pragma unroll
    for (int i = 0; i < 5; ++i) {
        int nt = wid + i * 4;
        if (nt >= 19) break;
        int n = nt * 16 + l15;
#pragma unroll
        for (int r = 0; r < 4; ++r) {
            int m = quad * 4 + r;
            float v = 0.f;
            if (n < 300) {
                v = acc[i][r] + b_d1[n];
                v = (v > 0.f) ? v : 0.01f * v;
            }
            X1[(size_t)(m0 + m) * 320 + n] = (__bf16)v;
        }
    }
    { // zero pad cols 304..319
        int m = t >> 4, c = 304 + (t & 15);
        X1[(size_t)(m0 + m) * 320 + c] = (__bf16)0.f;
    }
}

// ---------------- decoder stage 2: logits = X1 @ W_d2^T + b_d2 (masked) -----
__global__ __launch_bounds__(512) void dec2_k(const __bf16* __restrict__ X1,
                                              const __bf16* __restrict__ BpD2,
                                              const float* __restrict__ b_d2,
                                              const int* __restrict__ lengths,
                                              float* __restrict__ out) {
    __shared__ __align__(16) __bf16 As[64 * 328];
    __shared__ int validL[64];
    __shared__ int obase[64];
    int t = threadIdx.x, lane = t & 63, wid = t >> 6;
    int quad = lane >> 4, l15 = lane & 15;
    int mchunk = blockIdx.x % 184, nchunk = blockIdx.x / 184;
    int m0 = mchunk * 64;
    for (int c8 = t; c8 < 2560; c8 += 512) {
        int row = c8 / 40, col8 = c8 % 40;
        *(bf16x8*)(As + row * 328 + col8 * 8) =
            *(const bf16x8*)(X1 + (size_t)(m0 + row) * 320 + col8 * 8);
    }
    if (t < 64) {
        int row = m0 + t;
        int k = (row >> 9) + 1, b = row & 511;
        // dtype hedge: if lengths is int64, its int32 view has 0 at odd index
        // (values are 2..24, always >=2, so lengths32[1]==0 <=> int64).
        int is64 = (lengths[1] == 0);
        int lb = is64 ? lengths[2 * b] : lengths[b];
        validL[t] = (k < lb);
        obase[t] = b * ((T_ - 1) * V_) + (k - 1) * V_;
    }
    __syncthreads();
    int mt = wid >> 1, nb = (wid & 1) * 8;
    f32x4 z = {0.f, 0.f, 0.f, 0.f};
    f32x4 acc[8] = {z, z, z, z, z, z, z, z};
#pragma unroll
    for (int kt = 0; kt < 10; ++kt) {
        bf16x8 a = *(const bf16x8*)(As + (mt * 16 + l15) * 328 + quad * 8 + kt * 32);
#pragma unroll
        for (int j = 0; j < 8; ++j) {
            int ntg = nchunk * 16 + nb + j;
            if (ntg < 500) {
                bf16x8 b = *(const bf16x8*)(BpD2 + ((size_t)ntg * 10 + kt) * 64 * 8 + lane * 8);
                acc[j] = MF(a, b, acc[j]);
            }
        }
    }
#pragma unroll
    for (int j = 0; j < 8; ++j) {
        int ntg = nchunk * 16 + nb + j;
        if (ntg >= 500) break;
        int n = ntg * 16 + l15;
        float bias = b_d2[n];
#pragma unroll
        for (int r = 0; r < 4; ++r) {
            int m = mt * 16 + quad * 4 + r;
            float v = validL[m] ? (acc[j][r] + bias) : 0.f;
            out[(size_t)obase[m] + n] = v;
        }
    }
}

// ---------------------------------------------------------------------------
extern "C" void kernel_launch(void* const* d_in, const int* in_sizes, int n_in,
                              void* d_out, int out_size, void* d_ws, size_t ws_size,
                              hipStream_t stream) {
    const float* codes = (const float*)d_in[1];
    const int* lengths = (const int*)d_in[2];
    const float* W_emb = (const float*)d_in[3];
    const float* b_emb = (const float*)d_in[4];
    const float* W1 = (const float*)d_in[5];
    const float* W2 = (const float*)d_in[6];
    const float* W3 = (const float*)d_in[7];
    const float* W_u = (const float*)d_in[8];
    const float* b_u = (const float*)d_in[9];
    const float* W_ih = (const float*)d_in[10];
    const float* W_hh = (const float*)d_in[11];
    const float* b_ih = (const float*)d_in[12];
    const float* b_hh = (const float*)d_in[13];
    const float* W_d1 = (const float*)d_in[14];
    const float* b_d1 = (const float*)d_in[15];
    const float* W_d2 = (const float*)d_in[16];
    const float* b_d2 = (const float*)d_in[17];
    float* out = (float*)d_out;

    char* ws = (char*)d_ws;
    size_t off = 0;
    auto alloc = [&](size_t bytes) {
        size_t r = off;
        off += (bytes + 255) & ~(size_t)255;
        return r;
    };
    float*  g    = (float*)(ws + alloc((size_t)B_ * T_ * E_ * 4));
    float*  embT = (float*)(ws + alloc((size_t)V_ * E_ * 4));
    __bf16* BpOh = (__bf16*)(ws + alloc((size_t)3 * 21 * 11 * 64 * 8 * 2));
    __bf16* BpOl = (__bf16*)(ws + alloc((size_t)3 * 21 * 11 * 64 * 8 * 2));
    __bf16* BpFh = (__bf16*)(ws + alloc((size_t)6 * 11 * 64 * 8 * 2));
    __bf16* BpFl = (__bf16*)(ws + alloc((size_t)6 * 11 * 64 * 8 * 2));
    __bf16* BpHh = (__bf16*)(ws + alloc((size_t)6 * 1 * 64 * 8 * 2));
    __bf16* BpHl = (__bf16*)(ws + alloc((size_t)6 * 1 * 64 * 8 * 2));
    float*  Wf   = (float*)(ws + alloc((size_t)90 * 330 * 4));
    float*  bf_  = (float*)(ws + alloc((size_t)90 * 4));
    __bf16* Hs   = (__bf16*)(ws + alloc((size_t)11776 * 320 * 2));
    __bf16* X1   = (__bf16*)(ws + alloc((size_t)11776 * 320 * 2));
    __bf16* BpD1 = (__bf16*)(ws + alloc((size_t)19 * 10 * 64 * 8 * 2));
    __bf16* BpD2 = (__bf16*)(ws + alloc((size_t)500 * 10 * 64 * 8 * 2));

    // weight packing (hi/lo for the recurrent path)
    pack_hl<<<58, 256, 0, stream>>>(W1, BpOh, BpOl, 21, 11, 330, 330, 330);
    pack_hl<<<58, 256, 0, stream>>>(W2, BpOh + 118272, BpOl + 118272, 21, 11, 330, 330, 330);
    pack_hl<<<58, 256, 0, stream>>>(W3, BpOh + 236544, BpOl + 236544, 21, 11, 330, 330, 330);
    pack_hl<<<2, 256, 0, stream>>>(W_hh, BpHh, BpHl, 6, 1, 90, 30, 30);
    pack_b<<<48, 256, 0, stream>>>(W_d1, BpD1, 19, 10, 300, 300, 300);
    pack_b<<<1250, 256, 0, stream>>>(W_d2, BpD2, 500, 10, 8000, 300, 300);
    embt_k<<<9375, 256, 0, stream>>>(W_emb, embT);
    wfused_k<<<117, 256, 0, stream>>>(W_ih, W_u, b_ih, b_u, Wf, bf_);
    pack_hl<<<17, 256, 0, stream>>>(Wf, BpFh, BpFl, 6, 11, 90, 330, 330);

    // embedding
    embed_k<<<3072, 256, 0, stream>>>(codes, embT, b_emb, g);

    // recurrent chain (the critical path)
    chain_k<<<32, 1024, 0, stream>>>(g, BpOh, BpOl, BpFh, BpFl, BpHh, BpHl, bf_, b_hh, Hs);

    // decoder
    dec1_k<<<736, 256, 0, stream>>>(Hs, BpD1, b_d1, X1);
    dec2_k<<<184 * 32, 512, 0, stream>>>(X1, BpD2, b_d2, lengths, out);
}